// Round 1
// baseline (5526.414 us; speedup 1.0000x reference)
//
#include <hip/hip_runtime.h>
#include <hip/hip_fp16.h>

#define T_LEN 4096
#define BATCH 256
#define HID   25
#define G4    100   // 4*HID gates

__device__ __forceinline__ float sigmoidf_(float x) {
    return 1.0f / (1.0f + __expf(-x));
}
__device__ __forceinline__ float tanhf_(float x) {
    // 1 - 2/(exp(2x)+1): exact at 0, saturates correctly at +-inf
    return 1.0f - 2.0f / (__expf(2.0f * x) + 1.0f);
}

// 4-way split accumulation: avoids a serial 25-deep FMA dependency chain
template<int N>
__device__ __forceinline__ float dot_n(const float* __restrict__ w, const float* __restrict__ v) {
    float s0 = 0.f, s1 = 0.f, s2 = 0.f, s3 = 0.f;
    #pragma unroll
    for (int k = 0; k + 3 < N; k += 4) {
        s0 += w[k]   * v[k];
        s1 += w[k+1] * v[k+1];
        s2 += w[k+2] * v[k+2];
        s3 += w[k+3] * v[k+3];
    }
    #pragma unroll
    for (int k = (N / 4) * 4; k < N; ++k) s0 += w[k] * v[k];
    return (s0 + s1) + (s2 + s3);
}

// ---------------- Layer 0, both directions. One block per (batch, dir). ----------------
__global__ __launch_bounds__(128) void lstm_l0_kernel(
    const float* __restrict__ x,
    const float* __restrict__ w_ih_f, const float* __restrict__ w_hh_f,
    const float* __restrict__ b_ih_f, const float* __restrict__ b_hh_f,
    const float* __restrict__ w_ih_b, const float* __restrict__ w_hh_b,
    const float* __restrict__ b_ih_b, const float* __restrict__ b_hh_b,
    __half* __restrict__ h0)                 // [B, T, 50]  (fwd 0..24 | bwd 25..49)
{
    const int b   = blockIdx.x;
    const int dir = blockIdx.y;
    const int tid = threadIdx.x;

    const float* w_ih = dir ? w_ih_b : w_ih_f;
    const float* w_hh = dir ? w_hh_b : w_hh_f;

    __shared__ float h_lds[HID];
    __shared__ float act[G4];
    __shared__ float xb[4][HID];             // ring of prefetched x rows

    float wih[HID], whh[HID], bias = 0.0f;
    if (tid < G4) {
        #pragma unroll
        for (int k = 0; k < HID; ++k) {
            wih[k] = w_ih[tid * HID + k];
            whh[k] = w_hh[tid * HID + k];
        }
        bias = dir ? (b_ih_b[tid] + b_hh_b[tid]) : (b_ih_f[tid] + b_hh_f[tid]);
    }
    if (tid < HID) h_lds[tid] = 0.0f;
    float c = 0.0f;

    const int t0 = dir ? (T_LEN - 1) : 0;
    const int st = dir ? -1 : 1;
    const size_t xbase = (size_t)b * T_LEN * HID;

    if (tid < HID) {
        xb[0][tid] = x[xbase + (size_t)t0 * HID + tid];
        xb[1][tid] = x[xbase + (size_t)(t0 + st) * HID + tid];
    }
    __syncthreads();

    float xg = 0.0f;
    if (tid < G4) xg = bias + dot_n<HID>(wih, xb[0]);

    int t = t0;
    for (int it = 0; it < T_LEN; ++it, t += st) {
        // phase A: gates from recurrent dot only (x-projection was precomputed)
        if (tid < G4) {
            float g = xg + dot_n<HID>(whh, h_lds);
            act[tid] = (tid >= 2 * HID && tid < 3 * HID) ? tanhf_(g) : sigmoidf_(g);
        }
        __syncthreads();

        // phase C (critical path): c/h update on lanes 0..24
        if (tid < HID) {
            c = act[HID + tid] * c + act[tid] * act[2 * HID + tid];
            float h = act[3 * HID + tid] * tanhf_(c);
            h_lds[tid] = h;
            h0[((size_t)b * T_LEN + t) * (2 * HID) + dir * HID + tid] = __float2half(h);
        }
        // off-path: prefetch x row t+2 (idle lanes 100..124)
        if (tid >= G4 && tid < G4 + HID && it + 2 < T_LEN) {
            xb[(it + 2) & 3][tid - G4] = x[xbase + (size_t)(t + 2 * st) * HID + (tid - G4)];
        }
        // off-path: x-projection for step t+1
        if (tid < G4 && it + 1 < T_LEN) {
            xg = bias + dot_n<HID>(wih, xb[(it + 1) & 3]);
        }
        __syncthreads();
    }
}

// ---------------- Layer 1 forward. One block per batch. Only final h is kept. ----------------
__global__ __launch_bounds__(128) void lstm_l1f_kernel(
    const __half* __restrict__ h0,           // [B, T, 50]
    const float* __restrict__ w_ih, const float* __restrict__ w_hh,
    const float* __restrict__ b_ih, const float* __restrict__ b_hh,
    float* __restrict__ hf)                   // [B, 25]
{
    const int b   = blockIdx.x;
    const int tid = threadIdx.x;

    __shared__ float h_lds[HID];
    __shared__ float act[G4];
    __shared__ float xb[4][2 * HID];

    float wih[2 * HID], whh[HID], bias = 0.0f;
    if (tid < G4) {
        #pragma unroll
        for (int k = 0; k < 2 * HID; ++k) wih[k] = w_ih[tid * (2 * HID) + k];
        #pragma unroll
        for (int k = 0; k < HID; ++k)     whh[k] = w_hh[tid * HID + k];
        bias = b_ih[tid] + b_hh[tid];
    }
    if (tid < HID) h_lds[tid] = 0.0f;
    float c = 0.0f;

    const size_t ibase = (size_t)b * T_LEN * (2 * HID);

    if (tid < HID) {
        const __half2* r0 = (const __half2*)(h0 + ibase);
        const __half2* r1 = (const __half2*)(h0 + ibase + 2 * HID);
        float2 v0 = __half22float2(r0[tid]);
        float2 v1 = __half22float2(r1[tid]);
        xb[0][2 * tid] = v0.x; xb[0][2 * tid + 1] = v0.y;
        xb[1][2 * tid] = v1.x; xb[1][2 * tid + 1] = v1.y;
    }
    __syncthreads();

    float xg = 0.0f;
    if (tid < G4) xg = bias + dot_n<2 * HID>(wih, xb[0]);

    for (int it = 0; it < T_LEN; ++it) {
        if (tid < G4) {
            float g = xg + dot_n<HID>(whh, h_lds);
            act[tid] = (tid >= 2 * HID && tid < 3 * HID) ? tanhf_(g) : sigmoidf_(g);
        }
        __syncthreads();

        if (tid < HID) {
            c = act[HID + tid] * c + act[tid] * act[2 * HID + tid];
            h_lds[tid] = act[3 * HID + tid] * tanhf_(c);
        }
        if (tid >= G4 && tid < G4 + HID && it + 2 < T_LEN) {
            const __half2* rr = (const __half2*)(h0 + ibase + (size_t)(it + 2) * (2 * HID));
            float2 v = __half22float2(rr[tid - G4]);
            xb[(it + 2) & 3][2 * (tid - G4)]     = v.x;
            xb[(it + 2) & 3][2 * (tid - G4) + 1] = v.y;
        }
        if (tid < G4 && it + 1 < T_LEN) {
            xg = bias + dot_n<2 * HID>(wih, xb[(it + 1) & 3]);
        }
        __syncthreads();
    }
    if (tid < HID) hf[b * HID + tid] = h_lds[tid];
}

// ---------------- Layer 1 backward (exactly 1 step at t=T-1, zero state) + FC head. ----------------
__global__ __launch_bounds__(128) void final_kernel(
    const __half* __restrict__ h0,
    const float* __restrict__ hf,
    const float* __restrict__ w_ih1b,
    const float* __restrict__ b_ih1b, const float* __restrict__ b_hh1b,
    const float* __restrict__ fc2_w, const float* __restrict__ fc2_b,
    float* __restrict__ out)
{
    const int b   = blockIdx.x;
    const int tid = threadIdx.x;

    __shared__ float inb[2 * HID];
    __shared__ float act[G4];
    __shared__ float hb[HID];

    if (tid < HID) {
        const __half2* rr = (const __half2*)(h0 + ((size_t)b * T_LEN + (T_LEN - 1)) * (2 * HID));
        float2 v = __half22float2(rr[tid]);
        inb[2 * tid] = v.x; inb[2 * tid + 1] = v.y;
    }
    __syncthreads();

    if (tid < G4) {
        float g = b_ih1b[tid] + b_hh1b[tid];
        #pragma unroll
        for (int k = 0; k < 2 * HID; ++k) g += w_ih1b[tid * (2 * HID) + k] * inb[k];
        act[tid] = (tid >= 2 * HID && tid < 3 * HID) ? tanhf_(g) : sigmoidf_(g);
    }
    __syncthreads();

    if (tid < HID) {
        float c = act[tid] * act[2 * HID + tid];     // c0 = 0, so forget term drops
        hb[tid] = act[3 * HID + tid] * tanhf_(c);
    }
    __syncthreads();

    if (tid == 0) {
        float s = fc2_b[0];
        #pragma unroll
        for (int k = 0; k < HID; ++k) s += fmaxf(hf[b * HID + k], 0.0f) * fc2_w[k];
        #pragma unroll
        for (int k = 0; k < HID; ++k) s += fmaxf(hb[k], 0.0f) * fc2_w[HID + k];
        s = fmaxf(s, 0.0f);
        out[b] = 1.0f / (1.0f + __expf(-s));
    }
}

extern "C" void kernel_launch(void* const* d_in, const int* in_sizes, int n_in,
                              void* d_out, int out_size, void* d_ws, size_t ws_size,
                              hipStream_t stream)
{
    const float* x        = (const float*)d_in[0];
    const float* w_ih_l0f = (const float*)d_in[1];
    const float* w_hh_l0f = (const float*)d_in[2];
    const float* b_ih_l0f = (const float*)d_in[3];
    const float* b_hh_l0f = (const float*)d_in[4];
    const float* w_ih_l0b = (const float*)d_in[5];
    const float* w_hh_l0b = (const float*)d_in[6];
    const float* b_ih_l0b = (const float*)d_in[7];
    const float* b_hh_l0b = (const float*)d_in[8];
    const float* w_ih_l1f = (const float*)d_in[9];
    const float* w_hh_l1f = (const float*)d_in[10];
    const float* b_ih_l1f = (const float*)d_in[11];
    const float* b_hh_l1f = (const float*)d_in[12];
    const float* w_ih_l1b = (const float*)d_in[13];
    // d_in[14..16]: w_hh_l1b (unused: h0=0), b_ih_l1b, b_hh_l1b
    const float* b_ih_l1b = (const float*)d_in[15];
    const float* b_hh_l1b = (const float*)d_in[16];
    const float* fc2_w    = (const float*)d_in[17];
    const float* fc2_b    = (const float*)d_in[18];
    float* out = (float*)d_out;

    // workspace: h0 [B,T,50] fp16 (104,857,600 B) + hf [B,25] f32 (25,600 B)
    __half* h0 = (__half*)d_ws;
    float*  hf = (float*)((char*)d_ws + (size_t)BATCH * T_LEN * 2 * HID * sizeof(__half));

    dim3 g0(BATCH, 2);
    lstm_l0_kernel<<<g0, 128, 0, stream>>>(x,
        w_ih_l0f, w_hh_l0f, b_ih_l0f, b_hh_l0f,
        w_ih_l0b, w_hh_l0b, b_ih_l0b, b_hh_l0b, h0);

    lstm_l1f_kernel<<<BATCH, 128, 0, stream>>>(h0,
        w_ih_l1f, w_hh_l1f, b_ih_l1f, b_hh_l1f, hf);

    final_kernel<<<BATCH, 128, 0, stream>>>(h0, hf,
        w_ih_l1b, b_ih_l1b, b_hh_l1b, fc2_w, fc2_b, out);
}

// Round 2
// 2334.878 us; speedup vs baseline: 2.3669x; 2.3669x over previous
//
#include <hip/hip_runtime.h>
#include <hip/hip_fp16.h>

#define T_LEN 4096
#define BATCH 256
#define HID   25
#define G4    100
#define CH    16
#define NCHUNK (T_LEN / CH)

#define DEV __device__ __forceinline__

DEV float rcpf_(float x){
#if __has_builtin(__builtin_amdgcn_rcpf)
    return __builtin_amdgcn_rcpf(x);
#else
    return 1.0f / x;
#endif
}

DEV float readlane_f(float v, int j){
#if __has_builtin(__builtin_amdgcn_readlane)
    return __int_as_float(__builtin_amdgcn_readlane(__float_as_int(v), j));
#else
    return __shfl(v, j);
#endif
}

DEV float dot2acc(unsigned w, unsigned xv, float acc){
#if __has_builtin(__builtin_amdgcn_fdot2)
    typedef _Float16 h2v __attribute__((ext_vector_type(2)));
    return __builtin_amdgcn_fdot2(__builtin_bit_cast(h2v, w),
                                  __builtin_bit_cast(h2v, xv), acc, false);
#else
    __half2 a = __builtin_bit_cast(__half2, w), b2 = __builtin_bit_cast(__half2, xv);
    float2 fa = __half22float2(a), fb = __half22float2(b2);
    return acc + fa.x * fb.x + fa.y * fb.y;
#endif
}

DEV void fence_lgkm(){ asm volatile("s_waitcnt lgkmcnt(0)" ::: "memory"); }
// raw barrier: no vmcnt drain (keeps producer's global loads in flight)
DEV void sync2(){ fence_lgkm(); __builtin_amdgcn_s_barrier(); asm volatile("" ::: "memory"); }

// ================= Layer 0: one block per (batch, dir); wave0=recurrence, wave1=xg producer =================
__global__ __launch_bounds__(128, 1) void lstm_l0(
    const float* __restrict__ x,
    const float* __restrict__ w_ih_f, const float* __restrict__ w_hh_f,
    const float* __restrict__ b_ih_f, const float* __restrict__ b_hh_f,
    const float* __restrict__ w_ih_b, const float* __restrict__ w_hh_b,
    const float* __restrict__ b_ih_b, const float* __restrict__ b_hh_b,
    __half* __restrict__ h0)                       // [B,T,50]
{
    const int b    = blockIdx.x;
    const int dir  = blockIdx.y;
    const int tid  = threadIdx.x;
    const int lane = tid & 63;
    const int wave = tid >> 6;

    const float* w_ih = dir ? w_ih_b : w_ih_f;
    const float* w_hh = dir ? w_hh_b : w_hh_f;
    const float* b_ih = dir ? b_ih_b : b_ih_f;
    const float* b_hh = dir ? b_hh_b : b_hh_f;

    __shared__ float xg[2][CH][G4];                // xg ring (f32)
    __shared__ __align__(16) float xs[CH][28];     // staged x rows (padded)

    if (wave == 1) {
        // -------- producer: xg[t][g] = w_ih[g,:] . x[t,:] --------
        const int g0 = (lane < 50) ? lane : 0;
        const int g1 = g0 + 50;
        float w0[HID], w1[HID];
        #pragma unroll
        for (int k = 0; k < HID; ++k) { w0[k] = w_ih[g0*HID+k]; w1[k] = w_ih[g1*HID+k]; }

        for (int cc = 0; cc <= NCHUNK; ++cc) {
            if (cc < NCHUNK) {
                const int row0 = dir ? (T_LEN - CH - cc*CH) : (cc*CH);
                const float* src = x + ((size_t)b * T_LEN + row0) * HID;
                #pragma unroll
                for (int i = 0; i < 7; ++i) {
                    int idx = lane + 64*i;
                    if (idx < CH*HID) {
                        float v = src[idx];
                        int r = idx / HID, col = idx - r*HID;
                        xs[dir ? (CH-1-r) : r][col] = v;   // reverse rows for bwd dir
                    }
                }
                fence_lgkm();
                float (*dst)[G4] = xg[cc & 1];
                for (int t = 0; t < CH; ++t) {
                    const float* xr = xs[t];
                    float accA[4] = {0,0,0,0}, accB[4] = {0,0,0,0};
                    #pragma unroll
                    for (int k = 0; k < HID; ++k) {
                        float xv = xr[k];
                        accA[k & 3] += w0[k] * xv;
                        accB[k & 3] += w1[k] * xv;
                    }
                    if (lane < 50) {
                        dst[t][g0] = (accA[0]+accA[1]) + (accA[2]+accA[3]);
                        dst[t][g1] = (accB[0]+accB[1]) + (accB[2]+accB[3]);
                    }
                }
            }
            sync2();
        }
    } else {
        // -------- consumer: the recurrence, single wave, no barriers inside chunk --------
        // lane k<25: gA=f[k], gB=o[k]; lane 25+k: gA=i[k], gB=g[k]
        const int gA = (lane < 25) ? (25 + lane) : ((lane < 50) ? (lane - 25) : 0);
        const int gB = gA + 50;
        const float cb = (lane >= 25 && lane < 50) ? 2.0f : 1.0f;  // tanh for g-gate
        float whhA[HID], whhB[HID];
        #pragma unroll
        for (int k = 0; k < HID; ++k) { whhA[k] = w_hh[gA*HID+k]; whhB[k] = w_hh[gB*HID+k]; }
        const float biasA = b_ih[gA] + b_hh[gA];
        const float biasB = b_ih[gB] + b_hh[gB];

        float h = 0.0f, cst = 0.0f;
        size_t hoff = ((size_t)b * T_LEN + (dir ? (T_LEN-1) : 0)) * (2*HID) + (size_t)(dir*HID) + lane;
        const long long hstride = dir ? -(long long)(2*HID) : (long long)(2*HID);

        sync2();                                   // wait for chunk 0
        for (int c = 0; c < NCHUNK; ++c) {
            const float (*src)[G4] = xg[c & 1];
            #pragma unroll 4
            for (int t = 0; t < CH; ++t) {
                float xa = src[t][gA];
                float xb = src[t][gB];
                float dA[4] = {0,0,0,0}, dB[4] = {0,0,0,0};
                #pragma unroll
                for (int j = 0; j < HID; ++j) {
                    float hs = readlane_f(h, j);
                    dA[j & 3] += whhA[j] * hs;
                    dB[j & 3] += whhB[j] * hs;
                }
                float gAv = biasA + xa + ((dA[0]+dA[1]) + (dA[2]+dA[3]));
                float gBv = biasB + xb + ((dB[0]+dB[1]) + (dB[2]+dB[3]));
                float sA = 1.0f - rcpf_(__expf(gAv) + 1.0f);             // sigmoid
                float sB = 1.0f - cb * rcpf_(__expf(cb * gBv) + 1.0f);   // sigmoid or tanh
                float p  = sA * sB;                    // lanes 25..49: sig(i)*tanh(g)
                float ps = __shfl(p, lane + 25);       // lane k pulls from lane 25+k
                cst = sA * cst + ps;                   // lanes 0..24: sig(f)*c + i*g
                float th = 1.0f - 2.0f * rcpf_(__expf(2.0f * cst) + 1.0f);
                h = (lane < 25) ? (sB * th) : 0.0f;    // sig(o)*tanh(c)
                if (lane < 25) h0[hoff] = __float2half(h);
                hoff += hstride;
            }
            sync2();
        }
    }
}

// ================= Layer 1 forward: one block per batch; only final h kept =================
__global__ __launch_bounds__(128, 1) void lstm_l1f(
    const __half* __restrict__ h0,                 // [B,T,50]
    const float* __restrict__ w_ih, const float* __restrict__ w_hh,
    const float* __restrict__ b_ih, const float* __restrict__ b_hh,
    float* __restrict__ hf)                        // [B,25]
{
    const int b    = blockIdx.x;
    const int tid  = threadIdx.x;
    const int lane = tid & 63;
    const int wave = tid >> 6;

    __shared__ float xg[2][CH][G4];
    __shared__ __align__(16) unsigned xs[CH][28];  // rows of 25 dwords = 50 halves

    if (wave == 1) {
        const int g0 = (lane < 50) ? lane : 0;
        const int g1 = g0 + 50;
        unsigned wp0[HID], wp1[HID];
        #pragma unroll
        for (int k = 0; k < HID; ++k) {
            __half2 a  = __floats2half2_rn(w_ih[g0*(2*HID)+2*k], w_ih[g0*(2*HID)+2*k+1]);
            __half2 c2 = __floats2half2_rn(w_ih[g1*(2*HID)+2*k], w_ih[g1*(2*HID)+2*k+1]);
            wp0[k] = __builtin_bit_cast(unsigned, a);
            wp1[k] = __builtin_bit_cast(unsigned, c2);
        }
        const unsigned* hsrc = (const unsigned*)h0;
        for (int cc = 0; cc <= NCHUNK; ++cc) {
            if (cc < NCHUNK) {
                const unsigned* src = hsrc + ((size_t)b * T_LEN + cc*CH) * HID;
                #pragma unroll
                for (int i = 0; i < 7; ++i) {
                    int idx = lane + 64*i;
                    if (idx < CH*HID) {
                        unsigned v = src[idx];
                        int r = idx / HID, col = idx - r*HID;
                        xs[r][col] = v;
                    }
                }
                fence_lgkm();
                float (*dst)[G4] = xg[cc & 1];
                for (int t = 0; t < CH; ++t) {
                    const unsigned* xr = xs[t];
                    float accA[4] = {0,0,0,0}, accB[4] = {0,0,0,0};
                    #pragma unroll
                    for (int k = 0; k < HID; ++k) {
                        unsigned xv = xr[k];
                        accA[k & 3] = dot2acc(wp0[k], xv, accA[k & 3]);
                        accB[k & 3] = dot2acc(wp1[k], xv, accB[k & 3]);
                    }
                    if (lane < 50) {
                        dst[t][g0] = (accA[0]+accA[1]) + (accA[2]+accA[3]);
                        dst[t][g1] = (accB[0]+accB[1]) + (accB[2]+accB[3]);
                    }
                }
            }
            sync2();
        }
    } else {
        const int gA = (lane < 25) ? (25 + lane) : ((lane < 50) ? (lane - 25) : 0);
        const int gB = gA + 50;
        const float cb = (lane >= 25 && lane < 50) ? 2.0f : 1.0f;
        float whhA[HID], whhB[HID];
        #pragma unroll
        for (int k = 0; k < HID; ++k) { whhA[k] = w_hh[gA*HID+k]; whhB[k] = w_hh[gB*HID+k]; }
        const float biasA = b_ih[gA] + b_hh[gA];
        const float biasB = b_ih[gB] + b_hh[gB];

        float h = 0.0f, cst = 0.0f;

        sync2();
        for (int c = 0; c < NCHUNK; ++c) {
            const float (*src)[G4] = xg[c & 1];
            #pragma unroll 4
            for (int t = 0; t < CH; ++t) {
                float xa = src[t][gA];
                float xb = src[t][gB];
                float dA[4] = {0,0,0,0}, dB[4] = {0,0,0,0};
                #pragma unroll
                for (int j = 0; j < HID; ++j) {
                    float hs = readlane_f(h, j);
                    dA[j & 3] += whhA[j] * hs;
                    dB[j & 3] += whhB[j] * hs;
                }
                float gAv = biasA + xa + ((dA[0]+dA[1]) + (dA[2]+dA[3]));
                float gBv = biasB + xb + ((dB[0]+dB[1]) + (dB[2]+dB[3]));
                float sA = 1.0f - rcpf_(__expf(gAv) + 1.0f);
                float sB = 1.0f - cb * rcpf_(__expf(cb * gBv) + 1.0f);
                float p  = sA * sB;
                float ps = __shfl(p, lane + 25);
                cst = sA * cst + ps;
                float th = 1.0f - 2.0f * rcpf_(__expf(2.0f * cst) + 1.0f);
                h = (lane < 25) ? (sB * th) : 0.0f;
            }
            sync2();
        }
        if (lane < 25) hf[b * HID + lane] = h;
    }
}

// ================= Layer 1 backward (1 step from zero state) + FC head =================
__global__ __launch_bounds__(128) void final_kernel(
    const __half* __restrict__ h0,
    const float* __restrict__ hf,
    const float* __restrict__ w_ih1b,
    const float* __restrict__ b_ih1b, const float* __restrict__ b_hh1b,
    const float* __restrict__ fc2_w, const float* __restrict__ fc2_b,
    float* __restrict__ out)
{
    const int b   = blockIdx.x;
    const int tid = threadIdx.x;

    __shared__ float inb[2 * HID];
    __shared__ float act[G4];
    __shared__ float hb[HID];

    if (tid < HID) {
        const __half2* rr = (const __half2*)(h0 + ((size_t)b * T_LEN + (T_LEN - 1)) * (2 * HID));
        float2 v = __half22float2(rr[tid]);
        inb[2 * tid] = v.x; inb[2 * tid + 1] = v.y;
    }
    __syncthreads();

    if (tid < G4) {
        float g = b_ih1b[tid] + b_hh1b[tid];
        #pragma unroll
        for (int k = 0; k < 2 * HID; ++k) g += w_ih1b[tid * (2 * HID) + k] * inb[k];
        act[tid] = (tid >= 2 * HID && tid < 3 * HID)
                 ? (1.0f - 2.0f * rcpf_(__expf(2.0f * g) + 1.0f))
                 : (1.0f - rcpf_(__expf(g) + 1.0f));
    }
    __syncthreads();

    if (tid < HID) {
        float c = act[tid] * act[2 * HID + tid];   // c0 = 0
        hb[tid] = act[3 * HID + tid] * (1.0f - 2.0f * rcpf_(__expf(2.0f * c) + 1.0f));
    }
    __syncthreads();

    if (tid == 0) {
        float s = fc2_b[0];
        #pragma unroll
        for (int k = 0; k < HID; ++k) s += fmaxf(hf[b * HID + k], 0.0f) * fc2_w[k];
        #pragma unroll
        for (int k = 0; k < HID; ++k) s += fmaxf(hb[k], 0.0f) * fc2_w[HID + k];
        s = fmaxf(s, 0.0f);
        out[b] = 1.0f / (1.0f + __expf(-s));
    }
}

extern "C" void kernel_launch(void* const* d_in, const int* in_sizes, int n_in,
                              void* d_out, int out_size, void* d_ws, size_t ws_size,
                              hipStream_t stream)
{
    const float* x        = (const float*)d_in[0];
    const float* w_ih_l0f = (const float*)d_in[1];
    const float* w_hh_l0f = (const float*)d_in[2];
    const float* b_ih_l0f = (const float*)d_in[3];
    const float* b_hh_l0f = (const float*)d_in[4];
    const float* w_ih_l0b = (const float*)d_in[5];
    const float* w_hh_l0b = (const float*)d_in[6];
    const float* b_ih_l0b = (const float*)d_in[7];
    const float* b_hh_l0b = (const float*)d_in[8];
    const float* w_ih_l1f = (const float*)d_in[9];
    const float* w_hh_l1f = (const float*)d_in[10];
    const float* b_ih_l1f = (const float*)d_in[11];
    const float* b_hh_l1f = (const float*)d_in[12];
    const float* w_ih_l1b = (const float*)d_in[13];
    const float* b_ih_l1b = (const float*)d_in[15];
    const float* b_hh_l1b = (const float*)d_in[16];
    const float* fc2_w    = (const float*)d_in[17];
    const float* fc2_b    = (const float*)d_in[18];
    float* out = (float*)d_out;

    __half* h0 = (__half*)d_ws;   // [B,T,50] fp16
    float*  hf = (float*)((char*)d_ws + (size_t)BATCH * T_LEN * 2 * HID * sizeof(__half));

    dim3 g0(BATCH, 2);
    lstm_l0<<<g0, 128, 0, stream>>>(x,
        w_ih_l0f, w_hh_l0f, b_ih_l0f, b_hh_l0f,
        w_ih_l0b, w_hh_l0b, b_ih_l0b, b_hh_l0b, h0);

    lstm_l1f<<<BATCH, 128, 0, stream>>>(h0,
        w_ih_l1f, w_hh_l1f, b_ih_l1f, b_hh_l1f, hf);

    final_kernel<<<BATCH, 128, 0, stream>>>(h0, hf,
        w_ih_l1b, b_ih_l1b, b_hh_l1b, fc2_w, fc2_b, out);
}